// Round 1
// baseline (457.576 us; speedup 1.0000x reference)
//
#include <hip/hip_runtime.h>
#include <math.h>

// ---------------------------------------------------------------------------
// SurfNetwork: hash-grid gather -> sigma product/normalize -> MLP 34->64->64->3
// MLP runs on bf16 MFMA (16x16x32). One ray (128 points) per 512-thread block,
// 8 waves, each wave = one M=16 row tile. Weights pre-packed to B-fragment
// order in d_ws by a setup kernel (same work every call; ws is re-poisoned).
//
// Memory model (rocprof-verified): kernel is bound by 12.58M random 64B line
// fetches from the 64MB grid table (~715MB @ ~3.4TB/s random ceiling). This
// version removes partially-exposed LDS/VALU overhead from the stage phase:
//   - A0 layout [point][blk0..3][8 u16], blk XOR-swizzled by (point&3):
//     one aligned ds_write_b64 per gathered element (was 3x ds_write_u16
//     at ~7-way bank conflict), ds_read_b128 swizzled on the A-frag read.
//   - all fp32->bf16 via v_cvt_pk_bf16_f32 (RNE, bit-identical to manual
//     round-nearest-even on normal inputs).
//   - both x loads + both gathers issued before any LDS consumption.
// Fragment layouts (guide-verified on gfx950):
//   A: lane holds A[m=lane&15][k=(lane>>4)*8+j], j=0..7
//   B: lane holds B[k=(lane>>4)*8+j][n=lane&15]
//   C: lane reg r holds C[row=(lane>>4)*4+r][col=lane&15]
// Geo k index remap: k' = level*4 + c (c=3 is zero pad); levels 6,7 (blk 3)
// are zero in both A (explicit LDS zero) and B (zero weights).
// ---------------------------------------------------------------------------

typedef short bf16x8 __attribute__((ext_vector_type(8)));
typedef float floatx4 __attribute__((ext_vector_type(4)));
typedef float f32x4  __attribute__((ext_vector_type(4)));

__device__ inline unsigned short f2b(float f) {  // fp32 -> bf16 RNE (host-side pack kernel)
    union { float f; unsigned u; } v; v.f = f;
    unsigned r = v.u + 0x7FFF + ((v.u >> 16) & 1);
    return (unsigned short)(r >> 16);
}

// one-instruction packed RNE convert: lo16 = bf16(a), hi16 = bf16(b)
__device__ inline unsigned cvt_pk_bf16(float a, float b) {
    unsigned r;
    asm("v_cvt_pk_bf16_f32 %0, %1, %2" : "=v"(r) : "v"(a), "v"(b));
    return r;
}

// ws layout (bf16/ushort units):
//   [0    .. 2047]  W0geo frags: f = ntile(0..3); k' = lev*4+c (pad 32)
//   [2048 .. 6143]  W1    frags: f = kstep*4 + ntile;  k 0..63
//   [6144 .. 7167]  W2    frags: f = kstep(0..1), N=16 pad; n<3 valid
__global__ void build_frags(const float* __restrict__ W0,
                            const float* __restrict__ W1,
                            const float* __restrict__ W2,
                            unsigned short* __restrict__ wsf) {
    int tid = blockIdx.x * blockDim.x + threadIdx.x;
    if (tid >= 7168) return;
    int lane, j, k, n;
    float val;
    if (tid < 2048) {
        int f = tid >> 9, r = tid & 511; lane = r >> 3; j = r & 7;
        int kp  = ((lane >> 4) * 8) + j;   // k' = level*4 + c  (A0 packed layout)
        int lev = kp >> 2, c = kp & 3;
        n = f * 16 + (lane & 15);
        val = (lev < 6 && c < 3) ? W0[(16 + lev * 3 + c) * 64 + n] : 0.0f;
    } else if (tid < 6144) {
        int e = tid - 2048;
        int f = e >> 9, r = e & 511; lane = r >> 3; j = r & 7;
        int ks = f >> 2, nt = f & 3;
        k = ks * 32 + ((lane >> 4) * 8) + j;
        n = nt * 16 + (lane & 15);
        val = W1[k * 64 + n];
    } else {
        int e = tid - 6144;
        int f = e >> 9, r = e & 511; lane = r >> 3; j = r & 7;
        k = f * 32 + ((lane >> 4) * 8) + j;
        n = lane & 15;
        val = (n < 3) ? W2[k * 3 + n] : 0.0f;
    }
    wsf[tid] = f2b(val);
}

__global__ __launch_bounds__(512, 8) void surf_main(
    const int*   __restrict__ x,     // (B, 128, 6)
    const float* __restrict__ dvec,  // (B, 16)
    const float* __restrict__ gw,    // (TABLE, 4)
    const float* __restrict__ W0,    // (34, 64)  (dir rows used here)
    const float* __restrict__ b0,    // (64)
    const float* __restrict__ b1,    // (64)
    const float* __restrict__ b2,    // (3)
    const unsigned short* __restrict__ wsf,
    float* __restrict__ out_sigma,   // (B, 128)
    float* __restrict__ out_color)   // (B, 3)
{
    const int b    = blockIdx.x;
    const int t    = threadIdx.x;
    const int lane = t & 63;
    const int w    = t >> 6;         // wave id 0..7 -> rows w*16..w*16+15
    const int l15  = lane & 15;
    const int quad = lane >> 4;

    // A0: [point][blk][8 u16]; blk = level>>1, XOR-swizzled by (point&3).
    __shared__ __align__(16) unsigned short A0[128 * 32];
    __shared__ unsigned short H1[128 * 72];  // hidden bf16, stride 72 (reused for h2)
    __shared__ float s_sigl[768];            // clipped level densities, x memory order
    __shared__ float s_dirW[64];             // b0 + d[b] @ W0[0:16,:]
    __shared__ float s_wmax[2];
    __shared__ float s_cw[128];              // compositing weights
    __shared__ float s_part[8 * 16];

    const size_t b768 = (size_t)b * 768;

    // ---- phase A: issue ALL global loads up front (x + both gathers) ----
    int xv1 = x[b768 + t];                               // e1 = t (always < 768)
    int xv2 = (w < 4) ? x[b768 + 512 + t] : 0;           // e2 = 512+t, waves 0-3 only
    f32x4 v1 = *(const f32x4*)(gw + (size_t)xv1 * 4);
    f32x4 v2 = {};
    if (w < 4) v2 = *(const f32x4*)(gw + (size_t)xv2 * 4);

    // ---- independent work while gathers are in flight ----
    bf16x8 bw0[4], bw1[8];                   // weight B-fragments (L1/L2-resident)
    #pragma unroll
    for (int i = 0; i < 4; ++i) bw0[i] = *(const bf16x8*)(wsf + i * 512 + lane * 8);
    #pragma unroll
    for (int i = 0; i < 8; ++i) bw1[i] = *(const bf16x8*)(wsf + 2048 + i * 512 + lane * 8);

    if (t < 128) {  // zero blk 3 (levels 6,7 pad) so A-frag never reads garbage
        int p = t;
        *(uint4*)(A0 + p * 32 + ((3 ^ (p & 3)) << 3)) = make_uint4(0u, 0u, 0u, 0u);
    }
    if (t < 64) {   // per-ray direction contribution (fp32)
        float acc = b0[t];
        const float* db = dvec + (size_t)b * 16;
        #pragma unroll
        for (int i = 0; i < 16; ++i) acc = fmaf(db[i], W0[i * 64 + t], acc);
        s_dirW[t] = acc;
    }

    // ---- consume gathers: 1x ds_write_b64 per element (swizzled blk) ----
    {
        int e = t, p = e / 6, l = e - p * 6;
        s_sigl[e] = fminf(fmaxf(v1.x, 0.0f), 1.0f);
        uint2 pk;
        pk.x = cvt_pk_bf16(v1.y, v1.z);
        pk.y = cvt_pk_bf16(v1.w, 0.0f);
        *(uint2*)(A0 + p * 32 + (((l >> 1) ^ (p & 3)) << 3) + ((l & 1) << 2)) = pk;
    }
    if (w < 4) {
        int e = 512 + t, p = e / 6, l = e - p * 6;
        s_sigl[e] = fminf(fmaxf(v2.x, 0.0f), 1.0f);
        uint2 pk;
        pk.x = cvt_pk_bf16(v2.y, v2.z);
        pk.y = cvt_pk_bf16(v2.w, 0.0f);
        *(uint2*)(A0 + p * 32 + (((l >> 1) ^ (p & 3)) << 3) + ((l & 1) << 2)) = pk;
    }
    __syncthreads();

    // ---- sigma: product of 6 clipped densities, max over ray, normalize ----
    float sigma0 = 0.0f;
    if (t < 128) {
        float p = 1.0f;
        #pragma unroll
        for (int l = 0; l < 6; ++l) p *= s_sigl[t * 6 + l];
        sigma0 = p + 1e-4f;
        float m = sigma0;
        #pragma unroll
        for (int off = 32; off; off >>= 1) m = fmaxf(m, __shfl_xor(m, off));
        if (lane == 0) s_wmax[w] = m;
    }
    __syncthreads();
    if (t < 128) {
        float maxv  = fmaxf(s_wmax[0], s_wmax[1]);
        float sigma = sigma0 / maxv;
        out_sigma[(size_t)b * 128 + t] = sigma;
        float cw;
        if (t == 0) cw = sigma;
        else {
            float pp = 1.0f;
            #pragma unroll
            for (int l = 0; l < 6; ++l) pp *= s_sigl[(t - 1) * 6 + l];
            float sprev = (pp + 1e-4f) / maxv;
            cw = (1.0f - sprev) * sigma;
        }
        s_cw[t] = cw;
    }

    // ---- layer 0 (geo part via MFMA, dir part as fp32 C-init) ----
    const int row = w * 16 + l15;
    const int swz = l15 & 3;                 // same XOR as the write side (p = row)
    bf16x8 a0 = *(const bf16x8*)(A0 + row * 32 + ((quad ^ swz) << 3));
    floatx4 acc0[4];
    #pragma unroll
    for (int nt = 0; nt < 4; ++nt) {
        float dw = s_dirW[nt * 16 + l15];
        acc0[nt] = (floatx4){dw, dw, dw, dw};
        acc0[nt] = __builtin_amdgcn_mfma_f32_16x16x32_bf16(a0, bw0[nt], acc0[nt], 0, 0, 0);
    }
    // relu -> bf16 -> LDS in A-layout (wave-private rows; in-wave LDS order is safe)
    #pragma unroll
    for (int nt = 0; nt < 4; ++nt)
        #pragma unroll
        for (int r = 0; r < 4; ++r) {
            int pr = w * 16 + quad * 4 + r;
            H1[pr * 72 + nt * 16 + l15] =
                (unsigned short)cvt_pk_bf16(fmaxf(acc0[nt][r], 0.0f), 0.0f);
        }

    // ---- layer 1 (64x64) ----
    bf16x8 a1a = *(const bf16x8*)(H1 + row * 72 + quad * 8);
    bf16x8 a1b = *(const bf16x8*)(H1 + row * 72 + 32 + quad * 8);
    floatx4 acc1[4];
    #pragma unroll
    for (int nt = 0; nt < 4; ++nt) {
        float bb = b1[nt * 16 + l15];
        acc1[nt] = (floatx4){bb, bb, bb, bb};
        acc1[nt] = __builtin_amdgcn_mfma_f32_16x16x32_bf16(a1a, bw1[nt],     acc1[nt], 0, 0, 0);
        acc1[nt] = __builtin_amdgcn_mfma_f32_16x16x32_bf16(a1b, bw1[4 + nt], acc1[nt], 0, 0, 0);
    }
    // relu -> bf16 -> LDS (overwrite own rows)
    #pragma unroll
    for (int nt = 0; nt < 4; ++nt)
        #pragma unroll
        for (int r = 0; r < 4; ++r) {
            int pr = w * 16 + quad * 4 + r;
            H1[pr * 72 + nt * 16 + l15] =
                (unsigned short)cvt_pk_bf16(fmaxf(acc1[nt][r], 0.0f), 0.0f);
        }

    // ---- layer 2 (64->3, N padded to 16) ----
    bf16x8 bw2a = *(const bf16x8*)(wsf + 6144 + lane * 8);
    bf16x8 bw2b = *(const bf16x8*)(wsf + 6144 + 512 + lane * 8);
    bf16x8 a2a = *(const bf16x8*)(H1 + row * 72 + quad * 8);
    bf16x8 a2b = *(const bf16x8*)(H1 + row * 72 + 32 + quad * 8);
    float bias2 = (l15 < 3) ? b2[l15] : 0.0f;
    floatx4 acc2 = (floatx4){bias2, bias2, bias2, bias2};
    acc2 = __builtin_amdgcn_mfma_f32_16x16x32_bf16(a2a, bw2a, acc2, 0, 0, 0);
    acc2 = __builtin_amdgcn_mfma_f32_16x16x32_bf16(a2b, bw2b, acc2, 0, 0, 0);

    __syncthreads();  // s_cw ready
    // sigmoid + compositing weight + reduce over the wave's 16 points
    float sum = 0.0f;
    #pragma unroll
    for (int r = 0; r < 4; ++r) {
        float col = 1.0f / (1.0f + __expf(-acc2[r]));
        float cw  = s_cw[w * 16 + quad * 4 + r];
        sum += cw * col;
    }
    sum += __shfl_xor(sum, 16);
    sum += __shfl_xor(sum, 32);
    if (lane < 16) s_part[w * 16 + lane] = sum;   // col = lane
    __syncthreads();
    if (t < 3) {
        float o = 0.0f;
        #pragma unroll
        for (int ww = 0; ww < 8; ++ww) o += s_part[ww * 16 + t];
        out_color[(size_t)b * 3 + t] = o;
    }
}

extern "C" void kernel_launch(void* const* d_in, const int* in_sizes, int n_in,
                              void* d_out, int out_size, void* d_ws, size_t ws_size,
                              hipStream_t stream) {
    const int*   x    = (const int*)d_in[0];
    const float* dvec = (const float*)d_in[1];
    const float* gw   = (const float*)d_in[2];
    const float* W0   = (const float*)d_in[3];
    const float* b0   = (const float*)d_in[4];
    const float* W1   = (const float*)d_in[5];
    const float* b1   = (const float*)d_in[6];
    const float* W2   = (const float*)d_in[7];
    const float* b2   = (const float*)d_in[8];

    const int B = in_sizes[1] / 16;                       // d is (B, 16)
    float* out_sigma = (float*)d_out;                     // (B, 128)
    float* out_color = (float*)d_out + (size_t)B * 128;   // (B, 3)
    unsigned short* wsf = (unsigned short*)d_ws;          // 14336 B used

    build_frags<<<14, 512, 0, stream>>>(W0, W1, W2, wsf);
    surf_main<<<B, 512, 0, stream>>>(x, dvec, gw, W0, b0, b1, b2, wsf,
                                     out_sigma, out_color);
}

// Round 2
// 336.408 us; speedup vs baseline: 1.3602x; 1.3602x over previous
//
#include <hip/hip_runtime.h>
#include <math.h>

// ---------------------------------------------------------------------------
// SurfNetwork: hash-grid gather -> sigma product/normalize -> MLP 34->64->64->3
// MLP runs on bf16 MFMA (16x16x32). One ray (128 points) per 512-thread block,
// 8 waves, each wave = one M=16 row tile. Weights pre-packed to B-fragment
// order in d_ws by a setup kernel (same work every call; ws is re-poisoned).
//
// Memory model (rocprof-verified): kernel is bound by 12.58M random 64B line
// fetches from the 64MB grid table (~715MB @ ~3.4TB/s random ceiling).
//   - A0 layout [point][blk0..3][8 u16], blk XOR-swizzled by (point&3):
//     one aligned ds_write_b64 per gathered element, swizzled ds_read_b128.
//   - all fp32->bf16 via v_cvt_pk_bf16_f32 (RNE, bit-identical).
//   - both x loads + both gathers issued before any LDS consumption.
// __launch_bounds__(512, 4): measured-safe register budget (VGPR 40, no
// spill). (512,8) in round 1 clamped VGPR to 32 -> 262MB of scratch writes,
// +131us. LDS (31KB) caps us at 4 blocks/CU regardless, so 4 is correct.
// Fragment layouts (guide-verified on gfx950):
//   A: lane holds A[m=lane&15][k=(lane>>4)*8+j], j=0..7
//   B: lane holds B[k=(lane>>4)*8+j][n=lane&15]
//   C: lane reg r holds C[row=(lane>>4)*4+r][col=lane&15]
// Geo k index remap: k' = level*4 + c (c=3 is zero pad); levels 6,7 (blk 3)
// are zero in both A (explicit LDS zero) and B (zero weights).
// ---------------------------------------------------------------------------

typedef short bf16x8 __attribute__((ext_vector_type(8)));
typedef float floatx4 __attribute__((ext_vector_type(4)));
typedef float f32x4  __attribute__((ext_vector_type(4)));

__device__ inline unsigned short f2b(float f) {  // fp32 -> bf16 RNE (pack kernel)
    union { float f; unsigned u; } v; v.f = f;
    unsigned r = v.u + 0x7FFF + ((v.u >> 16) & 1);
    return (unsigned short)(r >> 16);
}

// one-instruction packed RNE convert: lo16 = bf16(a), hi16 = bf16(b)
__device__ inline unsigned cvt_pk_bf16(float a, float b) {
    unsigned r;
    asm("v_cvt_pk_bf16_f32 %0, %1, %2" : "=v"(r) : "v"(a), "v"(b));
    return r;
}

// ws layout (bf16/ushort units):
//   [0    .. 2047]  W0geo frags: f = ntile(0..3); k' = lev*4+c (pad 32)
//   [2048 .. 6143]  W1    frags: f = kstep*4 + ntile;  k 0..63
//   [6144 .. 7167]  W2    frags: f = kstep(0..1), N=16 pad; n<3 valid
__global__ void build_frags(const float* __restrict__ W0,
                            const float* __restrict__ W1,
                            const float* __restrict__ W2,
                            unsigned short* __restrict__ wsf) {
    int tid = blockIdx.x * blockDim.x + threadIdx.x;
    if (tid >= 7168) return;
    int lane, j, k, n;
    float val;
    if (tid < 2048) {
        int f = tid >> 9, r = tid & 511; lane = r >> 3; j = r & 7;
        int kp  = ((lane >> 4) * 8) + j;   // k' = level*4 + c  (A0 packed layout)
        int lev = kp >> 2, c = kp & 3;
        n = f * 16 + (lane & 15);
        val = (lev < 6 && c < 3) ? W0[(16 + lev * 3 + c) * 64 + n] : 0.0f;
    } else if (tid < 6144) {
        int e = tid - 2048;
        int f = e >> 9, r = e & 511; lane = r >> 3; j = r & 7;
        int ks = f >> 2, nt = f & 3;
        k = ks * 32 + ((lane >> 4) * 8) + j;
        n = nt * 16 + (lane & 15);
        val = W1[k * 64 + n];
    } else {
        int e = tid - 6144;
        int f = e >> 9, r = e & 511; lane = r >> 3; j = r & 7;
        k = f * 32 + ((lane >> 4) * 8) + j;
        n = lane & 15;
        val = (n < 3) ? W2[k * 3 + n] : 0.0f;
    }
    wsf[tid] = f2b(val);
}

__global__ __launch_bounds__(512, 4) void surf_main(
    const int*   __restrict__ x,     // (B, 128, 6)
    const float* __restrict__ dvec,  // (B, 16)
    const float* __restrict__ gw,    // (TABLE, 4)
    const float* __restrict__ W0,    // (34, 64)  (dir rows used here)
    const float* __restrict__ b0,    // (64)
    const float* __restrict__ b1,    // (64)
    const float* __restrict__ b2,    // (3)
    const unsigned short* __restrict__ wsf,
    float* __restrict__ out_sigma,   // (B, 128)
    float* __restrict__ out_color)   // (B, 3)
{
    const int b    = blockIdx.x;
    const int t    = threadIdx.x;
    const int lane = t & 63;
    const int w    = t >> 6;         // wave id 0..7 -> rows w*16..w*16+15
    const int l15  = lane & 15;
    const int quad = lane >> 4;

    // A0: [point][blk][8 u16]; blk = level>>1, XOR-swizzled by (point&3).
    __shared__ __align__(16) unsigned short A0[128 * 32];
    __shared__ unsigned short H1[128 * 72];  // hidden bf16, stride 72 (reused for h2)
    __shared__ float s_sigl[768];            // clipped level densities, x memory order
    __shared__ float s_dirW[64];             // b0 + d[b] @ W0[0:16,:]
    __shared__ float s_wmax[2];
    __shared__ float s_cw[128];              // compositing weights
    __shared__ float s_part[8 * 16];

    const size_t b768 = (size_t)b * 768;

    // ---- phase A: issue ALL global loads up front (x + both gathers) ----
    int xv1 = x[b768 + t];                               // e1 = t (always < 768)
    int xv2 = (w < 4) ? x[b768 + 512 + t] : 0;           // e2 = 512+t, waves 0-3 only
    f32x4 v1 = *(const f32x4*)(gw + (size_t)xv1 * 4);
    f32x4 v2 = {};
    if (w < 4) v2 = *(const f32x4*)(gw + (size_t)xv2 * 4);

    // ---- independent work while gathers are in flight ----
    bf16x8 bw0[4], bw1[8];                   // weight B-fragments (L1/L2-resident)
    #pragma unroll
    for (int i = 0; i < 4; ++i) bw0[i] = *(const bf16x8*)(wsf + i * 512 + lane * 8);
    #pragma unroll
    for (int i = 0; i < 8; ++i) bw1[i] = *(const bf16x8*)(wsf + 2048 + i * 512 + lane * 8);

    if (t < 128) {  // zero blk 3 (levels 6,7 pad) so A-frag never reads garbage
        int p = t;
        *(uint4*)(A0 + p * 32 + ((3 ^ (p & 3)) << 3)) = make_uint4(0u, 0u, 0u, 0u);
    }
    if (t < 64) {   // per-ray direction contribution (fp32)
        float acc = b0[t];
        const float* db = dvec + (size_t)b * 16;
        #pragma unroll
        for (int i = 0; i < 16; ++i) acc = fmaf(db[i], W0[i * 64 + t], acc);
        s_dirW[t] = acc;
    }

    // ---- consume gathers: 1x ds_write_b64 per element (swizzled blk) ----
    {
        int e = t, p = e / 6, l = e - p * 6;
        s_sigl[e] = fminf(fmaxf(v1.x, 0.0f), 1.0f);
        uint2 pk;
        pk.x = cvt_pk_bf16(v1.y, v1.z);
        pk.y = cvt_pk_bf16(v1.w, 0.0f);
        *(uint2*)(A0 + p * 32 + (((l >> 1) ^ (p & 3)) << 3) + ((l & 1) << 2)) = pk;
    }
    if (w < 4) {
        int e = 512 + t, p = e / 6, l = e - p * 6;
        s_sigl[e] = fminf(fmaxf(v2.x, 0.0f), 1.0f);
        uint2 pk;
        pk.x = cvt_pk_bf16(v2.y, v2.z);
        pk.y = cvt_pk_bf16(v2.w, 0.0f);
        *(uint2*)(A0 + p * 32 + (((l >> 1) ^ (p & 3)) << 3) + ((l & 1) << 2)) = pk;
    }
    __syncthreads();

    // ---- sigma: product of 6 clipped densities, max over ray, normalize ----
    float sigma0 = 0.0f;
    if (t < 128) {
        float p = 1.0f;
        #pragma unroll
        for (int l = 0; l < 6; ++l) p *= s_sigl[t * 6 + l];
        sigma0 = p + 1e-4f;
        float m = sigma0;
        #pragma unroll
        for (int off = 32; off; off >>= 1) m = fmaxf(m, __shfl_xor(m, off));
        if (lane == 0) s_wmax[w] = m;
    }
    __syncthreads();
    if (t < 128) {
        float maxv  = fmaxf(s_wmax[0], s_wmax[1]);
        float sigma = sigma0 / maxv;
        out_sigma[(size_t)b * 128 + t] = sigma;
        float cw;
        if (t == 0) cw = sigma;
        else {
            float pp = 1.0f;
            #pragma unroll
            for (int l = 0; l < 6; ++l) pp *= s_sigl[(t - 1) * 6 + l];
            float sprev = (pp + 1e-4f) / maxv;
            cw = (1.0f - sprev) * sigma;
        }
        s_cw[t] = cw;
    }

    // ---- layer 0 (geo part via MFMA, dir part as fp32 C-init) ----
    const int row = w * 16 + l15;
    const int swz = l15 & 3;                 // same XOR as the write side (p = row)
    bf16x8 a0 = *(const bf16x8*)(A0 + row * 32 + ((quad ^ swz) << 3));
    floatx4 acc0[4];
    #pragma unroll
    for (int nt = 0; nt < 4; ++nt) {
        float dw = s_dirW[nt * 16 + l15];
        acc0[nt] = (floatx4){dw, dw, dw, dw};
        acc0[nt] = __builtin_amdgcn_mfma_f32_16x16x32_bf16(a0, bw0[nt], acc0[nt], 0, 0, 0);
    }
    // relu -> bf16 -> LDS in A-layout (wave-private rows; in-wave LDS order is safe)
    #pragma unroll
    for (int nt = 0; nt < 4; ++nt)
        #pragma unroll
        for (int r = 0; r < 4; ++r) {
            int pr = w * 16 + quad * 4 + r;
            H1[pr * 72 + nt * 16 + l15] =
                (unsigned short)cvt_pk_bf16(fmaxf(acc0[nt][r], 0.0f), 0.0f);
        }

    // ---- layer 1 (64x64) ----
    bf16x8 a1a = *(const bf16x8*)(H1 + row * 72 + quad * 8);
    bf16x8 a1b = *(const bf16x8*)(H1 + row * 72 + 32 + quad * 8);
    floatx4 acc1[4];
    #pragma unroll
    for (int nt = 0; nt < 4; ++nt) {
        float bb = b1[nt * 16 + l15];
        acc1[nt] = (floatx4){bb, bb, bb, bb};
        acc1[nt] = __builtin_amdgcn_mfma_f32_16x16x32_bf16(a1a, bw1[nt],     acc1[nt], 0, 0, 0);
        acc1[nt] = __builtin_amdgcn_mfma_f32_16x16x32_bf16(a1b, bw1[4 + nt], acc1[nt], 0, 0, 0);
    }
    // relu -> bf16 -> LDS (overwrite own rows)
    #pragma unroll
    for (int nt = 0; nt < 4; ++nt)
        #pragma unroll
        for (int r = 0; r < 4; ++r) {
            int pr = w * 16 + quad * 4 + r;
            H1[pr * 72 + nt * 16 + l15] =
                (unsigned short)cvt_pk_bf16(fmaxf(acc1[nt][r], 0.0f), 0.0f);
        }

    // ---- layer 2 (64->3, N padded to 16) ----
    bf16x8 bw2a = *(const bf16x8*)(wsf + 6144 + lane * 8);
    bf16x8 bw2b = *(const bf16x8*)(wsf + 6144 + 512 + lane * 8);
    bf16x8 a2a = *(const bf16x8*)(H1 + row * 72 + quad * 8);
    bf16x8 a2b = *(const bf16x8*)(H1 + row * 72 + 32 + quad * 8);
    float bias2 = (l15 < 3) ? b2[l15] : 0.0f;
    floatx4 acc2 = (floatx4){bias2, bias2, bias2, bias2};
    acc2 = __builtin_amdgcn_mfma_f32_16x16x32_bf16(a2a, bw2a, acc2, 0, 0, 0);
    acc2 = __builtin_amdgcn_mfma_f32_16x16x32_bf16(a2b, bw2b, acc2, 0, 0, 0);

    __syncthreads();  // s_cw ready
    // sigmoid + compositing weight + reduce over the wave's 16 points
    float sum = 0.0f;
    #pragma unroll
    for (int r = 0; r < 4; ++r) {
        float col = 1.0f / (1.0f + __expf(-acc2[r]));
        float cw  = s_cw[w * 16 + quad * 4 + r];
        sum += cw * col;
    }
    sum += __shfl_xor(sum, 16);
    sum += __shfl_xor(sum, 32);
    if (lane < 16) s_part[w * 16 + lane] = sum;   // col = lane
    __syncthreads();
    if (t < 3) {
        float o = 0.0f;
        #pragma unroll
        for (int ww = 0; ww < 8; ++ww) o += s_part[ww * 16 + t];
        out_color[(size_t)b * 3 + t] = o;
    }
}

extern "C" void kernel_launch(void* const* d_in, const int* in_sizes, int n_in,
                              void* d_out, int out_size, void* d_ws, size_t ws_size,
                              hipStream_t stream) {
    const int*   x    = (const int*)d_in[0];
    const float* dvec = (const float*)d_in[1];
    const float* gw   = (const float*)d_in[2];
    const float* W0   = (const float*)d_in[3];
    const float* b0   = (const float*)d_in[4];
    const float* W1   = (const float*)d_in[5];
    const float* b1   = (const float*)d_in[6];
    const float* W2   = (const float*)d_in[7];
    const float* b2   = (const float*)d_in[8];

    const int B = in_sizes[1] / 16;                       // d is (B, 16)
    float* out_sigma = (float*)d_out;                     // (B, 128)
    float* out_color = (float*)d_out + (size_t)B * 128;   // (B, 3)
    unsigned short* wsf = (unsigned short*)d_ws;          // 14336 B used

    build_frags<<<14, 512, 0, stream>>>(W0, W1, W2, wsf);
    surf_main<<<B, 512, 0, stream>>>(x, dvec, gw, W0, b0, b1, b2, wsf,
                                     out_sigma, out_color);
}